// Round 1
// baseline (1423.579 us; speedup 1.0000x reference)
//
#include <hip/hip_runtime.h>
#include <hip/hip_bf16.h>

// Embedding gather: out[i, :] = weight[index[i], :]
// weight: [1,000,000 x 128] fp32 (512 MiB)
// index : [2,097,152] int32
// out   : [2,097,152 x 128] fp32 (1 GiB)
//
// Memory-bound. 32 lanes per row, one float4 (16 B) per lane -> one row =
// 512 B fully coalesced. Index load is wave-broadcast (same address for the
// 32 lanes of a row).

#define D_VEC4 32  // 128 floats / 4 per float4

__global__ __launch_bounds__(256) void Embedding_78795470013070_kernel(
    const float4* __restrict__ weight,   // [N_emb * 32] float4
    const int*    __restrict__ index,    // [n_index]
    float4*       __restrict__ out,      // [n_index * 32] float4
    int n_index)
{
    long long t = (long long)blockIdx.x * blockDim.x + threadIdx.x;
    long long row  = t >> 5;          // /32
    int       lane = (int)(t & 31);
    if (row < n_index) {
        long long src = (long long)index[row];
        out[row * D_VEC4 + lane] = weight[src * D_VEC4 + lane];
    }
}

extern "C" void kernel_launch(void* const* d_in, const int* in_sizes, int n_in,
                              void* d_out, int out_size, void* d_ws, size_t ws_size,
                              hipStream_t stream) {
    const float4* weight = (const float4*)d_in[0];
    const int*    index  = (const int*)d_in[1];
    float4*       out    = (float4*)d_out;
    const int n_index = in_sizes[1];           // 2,097,152

    const long long total_threads = (long long)n_index * D_VEC4;
    const int block = 256;
    const int grid  = (int)((total_threads + block - 1) / block);

    Embedding_78795470013070_kernel<<<grid, block, 0, stream>>>(
        weight, index, out, n_index);
}